// Round 12
// baseline (322.934 us; speedup 1.0000x reference)
//
#include <hip/hip_runtime.h>
#include <math.h>

typedef _Float16 h16;
typedef __attribute__((ext_vector_type(2))) _Float16 h16x2;
typedef __attribute__((ext_vector_type(4))) _Float16 h16x4;
typedef __attribute__((ext_vector_type(8))) _Float16 h16x8;
typedef __attribute__((ext_vector_type(4))) float f32x4;

#define NBATCH 2048
#define NT 64
#define KK 40
#define NL 7
#define SIGMA 0.02f
#define INVLN2 1.4426950408889634f

// LDS offsets in h16 units. Row stride 128 h16 (256 B) except U/G-planes (64).
// WT/HCK: SWZW (c ^ (row&15)<<3).  HNC/B2T/G/U: SWZ (c ^ (row&7)<<3).
#define WT   0                    // W^T packed (wr,wi): [48 l][128 c=2n+ri]
#define HCK  (48*128)             // H^H packed: [48 k][128 c=2n+ri] (hr,hi)
#define HNC  (HCK + 48*128)       // H interleaved: [64 n][96 c=2k+ri pad 128]
#define B2T  (HNC + 64*128)       // S then S' packed [48 l][96 c=2k+ri]
#define GRE  B2T                  // overlay after barrier: G_re plane [48 l][64 m]
#define GIM  (B2T + 48*64)        // overlay: G_im plane [48 l][64 m]
#define UOF  (B2T + 48*128)       // U [64 n][64 m] f16
#define LDSH (UOF + 64*64)        // 30720 h16 = 61440 B -> 2 blocks/CU

#define SWZ(row, c)  ((c) ^ (((row)&7)<<3))
#define SWZW(row, c) ((c) ^ (((row)&15)<<3))
#define MFMA16(a,b,c) __builtin_amdgcn_mfma_f32_16x16x32_f16((a),(b),(c),0,0,0)

static __device__ __forceinline__ float DOT2(h16x2 a, h16x2 b, float c) {
#if __has_builtin(__builtin_amdgcn_fdot2)
    return __builtin_amdgcn_fdot2(a, b, c, false);
#else
    return fmaf((float)a.x, (float)b.x, fmaf((float)a.y, (float)b.y, c));
#endif
}
static __device__ __forceinline__ h16x2 PK(float x, float y) {
    h16x2 r; r.x = (h16)x; r.y = (h16)y; return r;
}
// (wr,wi) -> (wi,-wr)
static __device__ __forceinline__ h16x2 SWNH(h16x2 w) {
    unsigned u = __builtin_bit_cast(unsigned, w);
    u = (u >> 16) | (u << 16);
    u ^= 0x80000000u;
    return __builtin_bit_cast(h16x2, u);
}
// per 32b word (sr',-si') -> (si',sr')
static __device__ __forceinline__ h16x8 imB(h16x8 v) {
    union { h16x8 h; unsigned u[4]; } x; x.h = v;
    #pragma unroll
    for (int i=0;i<4;++i){ unsigned t=x.u[i]; t=(t>>16)|(t<<16); x.u[i]=t^0x00008000u; }
    return x.h;
}
static __device__ __forceinline__ h16x2 GET8(h16x8 v, int i) {
    union { h16x8 w; h16x2 p[4]; } u; u.w = v; return u.p[i];
}

__global__ __launch_bounds__(256, 2) void gpnet_kernel(
    const float* __restrict__ gHr, const float* __restrict__ gHi,
    const float* __restrict__ gEta, const float* __restrict__ gU,
    const float* __restrict__ gB, float* __restrict__ gOut, int outFloats)
{
    __shared__ __align__(16) h16 sh[LDSH];
    __shared__ float sRed[4];

    const int tid = threadIdx.x;
    const int wv  = tid >> 6;      // wave 0..3
    const int ln  = tid & 63;
    const int col = ln & 15;       // fragment col / row component
    const int g   = ln >> 4;       // k-group

    const int bb = blockIdx.x;
    const float* hr = gHr + (size_t)bb * NT * KK;
    const float* hi = gHi + (size_t)bb * NT * KK;

    // ---- init: zero pads (uniform zeros -> raw stores are swizzle-safe)
    for (int i = tid; i < 512; i += 256) {
        *(h16x2*)(sh + WT  + 40*128 + 2*i) = PK(0.f, 0.f);   // Wt rows 40..47
        *(h16x2*)(sh + HCK + 40*128 + 2*i) = PK(0.f, 0.f);   // Hck rows 40..47
    }
    for (int i = tid; i < 512; i += 256) {                   // Hnc logical cols [80,96)
        int n = i >> 3, c = 80 + 2*(i & 7);
        *(h16x2*)(sh + HNC + n*128 + SWZ(n, c)) = PK(0.f, 0.f);
    }
    // H data (both layouts) + W^T = b0  (layer-0 collapse: W1 = b[0], Wi = 0)
    for (int i = tid; i < NT*KK; i += 256) {
        int n = i / KK, k = i % KK;
        float xr = hr[i], xi = hi[i];
        h16x2 p = PK(xr, xi);
        *(h16x2*)(sh + HCK + k*128 + SWZW(k, 2*n)) = p;
        *(h16x2*)(sh + HNC + n*128 + SWZ(n, 2*k)) = p;
        *(h16x2*)(sh + WT  + k*128 + SWZW(k, 2*n)) = PK(gB[i], 0.f);
    }
    // W-cache (f32 regs) = b0 at owned positions; power
    float Wr[3][4], Wi[3][4];
    float ps = 0.f;
    #pragma unroll
    for (int ct = 0; ct < 3; ++ct)
        #pragma unroll
        for (int r = 0; r < 4; ++r) {
            int n = 16*wv + 4*g + r, l = col + 16*ct;
            float b0 = (l < KK) ? gB[n*KK + l] : 0.f;
            Wr[ct][r] = b0; Wi[ct][r] = 0.f;
            ps += b0 * b0;
        }
    #pragma unroll
    for (int off = 32; off; off >>= 1) ps += __shfl_down(ps, off, 64);
    if (ln == 0) sRed[wv] = ps;
    __syncthreads();

    for (int t = 1; t < NL; ++t) {
        const float pw   = sRed[0] + sRed[1] + sRed[2] + sRed[3];
        const float cpen = 0.04f * (pw - 1.0f);
        const float etat = gEta[t];

        // b[t] prefetch at owned positions (used in phase C)
        float breg[3][4];
        #pragma unroll
        for (int ct = 0; ct < 3; ++ct)
            #pragma unroll
            for (int r = 0; r < 4; ++r) {
                int n = 16*wv + 4*g + r, l = col + 16*ct;
                breg[ct][r] = (l < KK) ? gB[(size_t)t*NT*KK + n*KK + l] : 0.f;
            }

        // ---- pad-zero B2T (G overlay dirtied it last layer; B reads it as S')
        for (int e = tid; e < 704; e += 256) {
            int l, k;
            if (e < 384) { l = 40 + e / 48; k = e % 48; }
            else { int f = e - 384; l = f >> 3; k = 40 + (f & 7); }
            *(h16x2*)(sh + B2T + l*128 + SWZ(l, 2*k)) = PK(0.f, 0.f);
        }

        // ---- PHASE A (scalar dot2): 4k x 4l tiles on 100 threads (waves 0-1);
        //      waves 2-3 stage U[t] -> LDS meanwhile.
        if (tid < 100) {
            const int k0 = (tid / 10) * 4;   // 0,4,...,36
            const int l0 = (tid % 10) * 4;   // 0,4,...,36
            float ar[4][4] = {}, ai[4][4] = {};
            #pragma unroll 2
            for (int c = 0; c < 16; ++c) {
                h16x8 wl[4], hv[4];
                #pragma unroll
                for (int j = 0; j < 4; ++j)
                    wl[j] = *(const h16x8*)(sh + WT + (l0+j)*128 + SWZW(l0+j, c*8));
                #pragma unroll
                for (int i = 0; i < 4; ++i)
                    hv[i] = *(const h16x8*)(sh + HCK + (k0+i)*128 + SWZW(k0+i, c*8));
                #pragma unroll
                for (int wd = 0; wd < 4; ++wd) {
                    #pragma unroll
                    for (int j = 0; j < 4; ++j) {
                        h16x2 wp = GET8(wl[j], wd);
                        h16x2 wn = SWNH(wp);
                        #pragma unroll
                        for (int i = 0; i < 4; ++i) {
                            h16x2 hp = GET8(hv[i], wd);
                            ar[i][j] = DOT2(wp, hp, ar[i][j]);        // Re
                            ai[i][j] = DOT2(wn, hp, ai[i][j]);        // Im
                        }
                    }
                }
            }
            // packed UNSCALED S^T writes: row l0+j, cols 2k0..2k0+7
            #pragma unroll
            for (int j = 0; j < 4; ++j) {
                h16x8 sv;
                #pragma unroll
                for (int i = 0; i < 4; ++i) {
                    sv[2*i]   = (h16)ar[i][j];
                    sv[2*i+1] = (h16)ai[i][j];
                }
                *(h16x8*)(sh + B2T + (l0+j)*128 + SWZ(l0+j, 2*k0)) = sv;
            }
        } else if (tid >= 128) {
            // waves 2-3: stage U[t] -> LDS (f16, swizzled); latency hidden by A
            const float2* u2 = (const float2*)(gU + (size_t)t * NT * NT);
            const int base = tid - 128;          // 0..127
            #pragma unroll
            for (int j = 0; j < 16; ++j) {
                int e2 = base + j*128;           // 0..2047
                float2 v = u2[e2];
                int n = e2 >> 5, m2 = (e2 & 31) * 2;
                *(h16x2*)(sh + UOF + n*64 + SWZ(n, m2)) = PK(v.x, v.y);
            }
        }
        __syncthreads();                       // (1) unscaled S + U ready

        // ---- coefficients: 4 lanes per user k; scale column k of S^T
        if (tid < 160) {
            const int k = tid >> 2, q = tid & 3;
            h16x2 va[10];
            #pragma unroll
            for (int ii = 0; ii < 10; ++ii)
                va[ii] = *(const h16x2*)(sh + B2T + (q*10+ii)*128 + SWZ(q*10+ii, 2*k));
            float rs = 0.f, dd = 0.f;
            #pragma unroll
            for (int ii = 0; ii < 10; ++ii) rs = DOT2(va[ii], va[ii], rs);
            const int dk = k - q*10;
            if (dk >= 0 && dk < 10) dd = DOT2(va[dk], va[dk], 0.f);
            rs += __shfl_xor(rs, 1, 64); rs += __shfl_xor(rs, 2, 64);
            dd += __shfl_xor(dd, 1, 64); dd += __shfl_xor(dd, 2, 64);
            float T  = rs + SIGMA, Is = rs - dd + SIGMA;
            float cA_ = 2.f * INVLN2 / T;
            float cC_ = -2.f * INVLN2 * dd / (Is * T);
            #pragma unroll
            for (int ii = 0; ii < 10; ++ii) {
                int l = q*10 + ii;
                float c = (l == k) ? cA_ : cC_;
                *(h16x2*)(sh + B2T + l*128 + SWZ(l, 2*k)) =
                    PK((float)va[ii].x * c, -(float)va[ii].y * c);   // (sr',-si')
            }
        }
        __syncthreads();                       // (2) S' ready

        // ---- PHASE B (MFMA): G[n][l], row-strip n in [16wv,16wv+16)
        f32x4 gRe[3], gIm[3];
        #pragma unroll
        for (int ct = 0; ct < 3; ++ct) { gRe[ct] = (f32x4){0.f,0.f,0.f,0.f}; gIm[ct] = (f32x4){0.f,0.f,0.f,0.f}; }
        {
            const int nrow = col + 16*wv;
            #pragma unroll
            for (int q = 0; q < 3; ++q) {
                h16x8 af = *(const h16x8*)(sh + HNC + nrow*128 + SWZ(nrow, g*8 + 32*q));
                #pragma unroll
                for (int ct = 0; ct < 3; ++ct) {
                    int lr = col + 16*ct;
                    h16x8 bf = *(const h16x8*)(sh + B2T + lr*128 + SWZ(lr, g*8 + 32*q));
                    gRe[ct] = MFMA16(af, bf, gRe[ct]);
                    gIm[ct] = MFMA16(af, imB(bf), gIm[ct]);
                }
            }
        }
        #pragma unroll
        for (int ct = 0; ct < 3; ++ct)
            #pragma unroll
            for (int r = 0; r < 4; ++r) {
                gRe[ct][r] -= cpen * Wr[ct][r];
                gIm[ct][r] -= cpen * Wi[ct][r];
            }
        __syncthreads();                       // (3) all B2t reads done
        // write G as split planes (packed h16x4): GRE[l][m], GIM[l][m], m = n
        {
            const int n0w = 16*wv + 4*g;
            #pragma unroll
            for (int ct = 0; ct < 3; ++ct) {
                int l = col + 16*ct;
                h16x4 g4, q4;
                #pragma unroll
                for (int r = 0; r < 4; ++r) { g4[r] = (h16)gRe[ct][r]; q4[r] = (h16)gIm[ct][r]; }
                *(h16x4*)(sh + GRE + l*64 + SWZ(l, n0w)) = g4;
                *(h16x4*)(sh + GIM + l*64 + SWZ(l, n0w)) = q4;
            }
        }
        __syncthreads();                       // (4) G planes visible

        // ---- PHASE C (MFMA): Ug = U x G ; W update; power fold
        f32x4 cRe[3], cIm[3];
        #pragma unroll
        for (int ct = 0; ct < 3; ++ct) { cRe[ct] = (f32x4){0.f,0.f,0.f,0.f}; cIm[ct] = (f32x4){0.f,0.f,0.f,0.f}; }
        {
            const int nrow = col + 16*wv;
            #pragma unroll
            for (int q = 0; q < 2; ++q) {
                h16x8 af = *(const h16x8*)(sh + UOF + nrow*64 + SWZ(nrow, g*8 + 32*q));
                #pragma unroll
                for (int ct = 0; ct < 3; ++ct) {
                    const int l = col + 16*ct;
                    h16x8 fre = *(const h16x8*)(sh + GRE + l*64 + SWZ(l, g*8 + 32*q));
                    h16x8 fim = *(const h16x8*)(sh + GIM + l*64 + SWZ(l, g*8 + 32*q));
                    cRe[ct] = MFMA16(af, fre, cRe[ct]);
                    cIm[ct] = MFMA16(af, fim, cIm[ct]);
                }
            }
        }
        float ps2 = 0.f;
        {
            const int n0w = 16*wv + 4*g;
            #pragma unroll
            for (int ct = 0; ct < 3; ++ct) {
                int l = col + 16*ct;
                h16x8 wvv;
                #pragma unroll
                for (int r = 0; r < 4; ++r) {
                    float ur = cRe[ct][r], ui = cIm[ct][r];
                    float wr = Wr[ct][r] - etat*(ur - ui) + breg[ct][r];
                    float wi = Wi[ct][r] - etat*(ui + ur);
                    Wr[ct][r] = wr; Wi[ct][r] = wi;
                    wvv[2*r]   = (h16)wr;
                    wvv[2*r+1] = (h16)wi;
                    if (l < KK) ps2 += wr*wr + wi*wi;
                }
                if (l < KK)
                    *(h16x8*)(sh + WT + l*128 + SWZW(l, 2*n0w)) = wvv;
            }
        }
        #pragma unroll
        for (int off = 32; off; off >>= 1) ps2 += __shfl_down(ps2, off, 64);
        if (ln == 0) sRed[wv] = ps2;
        __syncthreads();                       // (5) Wt + sRed ready
    }

    // ---- final normalization from registers
    const float pwf   = sRed[0] + sRed[1] + sRed[2] + sRed[3];
    const float scale = 1.0f / (sqrtf(pwf) + 1e-6f);

    if (outFloats >= 2 * NBATCH * NT * KK) {
        float2* ob = (float2*)(gOut + (size_t)bb * NT * KK * 2);
        #pragma unroll
        for (int ct = 0; ct < 3; ++ct)
            #pragma unroll
            for (int r = 0; r < 4; ++r) {
                int n = 16*wv + 4*g + r, l = col + 16*ct;
                if (l < KK) {
                    float2 v; v.x = Wr[ct][r]*scale; v.y = Wi[ct][r]*scale;
                    ob[n*KK + l] = v;
                }
            }
    } else {
        float* ob = gOut + (size_t)bb * NT * KK;
        #pragma unroll
        for (int ct = 0; ct < 3; ++ct)
            #pragma unroll
            for (int r = 0; r < 4; ++r) {
                int n = 16*wv + 4*g + r, l = col + 16*ct;
                if (l < KK) ob[n*KK + l] = Wr[ct][r] * scale;
            }
    }
}

extern "C" void kernel_launch(void* const* d_in, const int* in_sizes, int n_in,
                              void* d_out, int out_size, void* d_ws, size_t ws_size,
                              hipStream_t stream) {
    (void)in_sizes; (void)n_in; (void)d_ws; (void)ws_size;
    const float* Hr  = (const float*)d_in[0];
    const float* Hi  = (const float*)d_in[1];
    const float* eta = (const float*)d_in[2];
    const float* U   = (const float*)d_in[3];
    const float* b   = (const float*)d_in[4];
    float* out = (float*)d_out;
    gpnet_kernel<<<NBATCH, 256, 0, stream>>>(Hr, Hi, eta, U, b, out, out_size);
}